// Round 3
// baseline (4536.385 us; speedup 1.0000x reference)
//
#include <hip/hip_runtime.h>

typedef unsigned short ushort_t;
typedef __attribute__((ext_vector_type(8))) short short8;
typedef __attribute__((ext_vector_type(4))) float float4v;

#define HW 16384
#define A_BINS 180
#define R_BINS 182
#define AP 188              // A padded by 4 each side
#define CCH 64
#define NB 4
#define NC 256              // NB*CCH, nc-major inner dim of hough buffers
#define MROWS (A_BINS * R_BINS)      // 32760
#define MPROWS (AP * R_BINS)         // 34216
#define ACC_STRIDE 65                // LDS acc row stride (bank spread)

static __device__ __forceinline__ float b2f(ushort_t u) {
    union { unsigned u32; float f; } c; c.u32 = ((unsigned)u) << 16; return c.f;
}
static __device__ __forceinline__ float u2f(unsigned u) {
    union { unsigned u32; float f; } c; c.u32 = u; return c.f;
}
static __device__ __forceinline__ ushort_t f2b(float f) {
    union { float f; unsigned u; } c; c.f = f;
    unsigned r = c.u + 0x7fffu + ((c.u >> 16) & 1u);   // RNE
    return (ushort_t)(r >> 16);
}

// ---- prep: x [256][16384] f32 -> xb bf16 (same order) + xbT bf16 (spatial transpose) ----
__global__ __launch_bounds__(256) void k_prep(const float* __restrict__ x,
                                              ushort_t* __restrict__ xb,
                                              ushort_t* __restrict__ xbT) {
    __shared__ float tile[64][65];
    int t = threadIdx.x, lane = t & 63, g = t >> 6;
    int h0 = blockIdx.x * 64, w0 = blockIdx.y * 64;
    int nc = blockIdx.z;
    const float* xp = x + (size_t)nc * HW;
    ushort_t* xbp = xb + (size_t)nc * HW;
    ushort_t* xtp = xbT + (size_t)nc * HW;
#pragma unroll
    for (int i = 0; i < 16; ++i) {
        int hh = g + i * 4;
        float v = xp[(h0 + hh) * 128 + w0 + lane];
        tile[hh][lane] = v;
        xbp[(h0 + hh) * 128 + w0 + lane] = f2b(v);
    }
    __syncthreads();
#pragma unroll
    for (int i = 0; i < 16; ++i) {
        int ww = g + i * 4;
        xtp[(w0 + ww) * 128 + h0 + lane] = f2b(tile[lane][ww]);
    }
}

// ---- rhoT: spatial transpose of rho [180][128][128] int ----
__global__ __launch_bounds__(256) void k_rhoT(const int* __restrict__ rho,
                                              int* __restrict__ rhoT) {
    __shared__ int tile[64][65];
    int t = threadIdx.x, lane = t & 63, g = t >> 6;
    int h0 = blockIdx.x * 64, w0 = blockIdx.y * 64;
    int a = blockIdx.z;
    const int* rp = rho + (size_t)a * HW;
    int* rt = rhoT + (size_t)a * HW;
#pragma unroll
    for (int i = 0; i < 16; ++i) {
        int hh = g + i * 4;
        tile[hh][lane] = rp[(h0 + hh) * 128 + w0 + lane];
    }
    __syncthreads();
#pragma unroll
    for (int i = 0; i < 16; ++i) {
        int ww = g + i * 4;
        rt[(w0 + ww) * 128 + h0 + lane] = tile[lane][ww];
    }
}

// ---- zero the A-padding rows of the 3 padded nc-major buffers ----
__global__ __launch_bounds__(256) void k_zero_pads(ushort_t* __restrict__ ht0,
                                                   ushort_t* __restrict__ bufA,
                                                   ushort_t* __restrict__ bufB) {
    int b = blockIdx.x >> 3, j = blockIdx.x & 7;
    int ap = (j < 4) ? j : (184 + (j - 4));
    ushort_t* base = (b == 0 ? ht0 : (b == 1 ? bufA : bufB));
    uint4* p = (uint4*)(base + (size_t)ap * (R_BINS * NC));
    int n16 = R_BINS * NC / 8;      // uint4 = 8 ushorts
    for (int i = threadIdx.x; i < n16; i += 256) p[i] = (uint4){0, 0, 0, 0};
}

// ---- repack conv weights (64,64,9) f32 -> MFMA B-fragment bf16 ----
__global__ __launch_bounds__(256) void k_repack(const float* __restrict__ w2,
                                                const float* __restrict__ w3,
                                                ushort_t* __restrict__ w2b,
                                                ushort_t* __restrict__ w3b) {
    const float* w = blockIdx.y ? w3 : w2;
    ushort_t* wb = blockIdx.y ? w3b : w2b;
    int idx = blockIdx.x * 256 + threadIdx.x;   // 0..36863
    int j = idx & 7;
    int lane = (idx >> 3) & 63;
    int cot = (idx >> 9) & 3;
    int h = (idx >> 11) & 1;
    int k = idx >> 12;
    int co = cot * 16 + (lane & 15);
    int ci = h * 32 + (lane >> 4) * 8 + j;
    wb[idx] = f2b(w[(co * 64 + ci) * 9 + k]);
}

// ---- DHT: LDS fp32 accumulator scatter, lanes = pixels, orientation-selected ----
// block = (angle, batch). acc[bin][c] stride-65: bank = (bin + c) & 31, adjacent
// lanes have adjacent bins (|d rho/d lane| >= 0.707 by orientation choice).
__global__ __launch_bounds__(256) void k_dht_s(const ushort_t* __restrict__ xb,
                                               const ushort_t* __restrict__ xbT,
                                               const int* __restrict__ rho,
                                               const int* __restrict__ rhoT,
                                               ushort_t* __restrict__ ht0) {
    __shared__ float acc[R_BINS * ACC_STRIDE];   // 47,320 B
    int a = blockIdx.x, n = blockIdx.y;
    int t = threadIdx.x, lane = t & 63, wv = t >> 6;
    for (int i = t; i < R_BINS * ACC_STRIDE; i += 256) acc[i] = 0.f;
    __syncthreads();
    int hmaj = (a >= 45 && a < 135);
    const ushort_t* xs = (hmaj ? xbT : xb) + (size_t)(n * 64) * HW;
    const int* rs = (hmaj ? rhoT : rho) + (size_t)a * HW;
    for (int pb = wv * 64; pb < HW; pb += 256) {
        int idx = rs[pb + lane] * ACC_STRIDE;
        const ushort_t* xc = xs + pb + lane;
#pragma unroll 8
        for (int c = 0; c < 64; ++c) {
            atomicAdd(&acc[idx + c], b2f(xc[(size_t)c << 14]));
        }
    }
    __syncthreads();
    size_t ob = (size_t)(a + 4) * (R_BINS * NC) + n * 64;
    for (int i = t; i < R_BINS * CCH; i += 256) {
        int c = i & 63, r = i >> 6;
        ht0[ob + (size_t)r * NC + c] = f2b(acc[r * ACC_STRIDE + c]);
    }
}

// ---- depthwise (9,1) conv + bias + relu, nc-major ----
__global__ __launch_bounds__(256) void k_conv1(const ushort_t* __restrict__ ht0,
                                               const float* __restrict__ w1,
                                               const float* __restrict__ b1,
                                               ushort_t* __restrict__ bufA) {
    __shared__ float wl[576 + 64];
    int t = threadIdx.x;
    for (int i = t; i < 576; i += 256) wl[i] = w1[i];
    if (t < 64) wl[576 + t] = b1[t];
    __syncthreads();
    int c = t & 63;
    int r = blockIdx.x, a = blockIdx.y;
    float s = wl[576 + c];
    size_t base = ((size_t)a * R_BINS + r) * NC + t;
#pragma unroll
    for (int k = 0; k < 9; ++k)
        s += b2f(ht0[base + (size_t)k * (R_BINS * NC)]) * wl[c * 9 + k];
    bufA[((size_t)(a + 4) * R_BINS + r) * NC + t] = f2b(fmaxf(s, 0.f));
}

// ---- dense (9,1) conv as MFMA GEMM, nc-major strides ----
__global__ __launch_bounds__(256) void k_gemm(const ushort_t* __restrict__ in,
                                              const ushort_t* __restrict__ wb,
                                              const float* __restrict__ bias,
                                              ushort_t* __restrict__ out,
                                              int outRowOff) {
    int t = threadIdx.x, lane = t & 63, wv = t >> 6;
    int m = lane & 15, q = lane >> 4;
    int n = blockIdx.y;
    int rowBase = blockIdx.x * 64 + wv * 16;
    int row = rowBase + m;
    int rowc = row < MROWS ? row : (MROWS - 1);
    const ushort_t* inN = in + n * 64;
    float4v acc[4];
#pragma unroll
    for (int i = 0; i < 4; ++i) acc[i] = (float4v){0.f, 0.f, 0.f, 0.f};

#pragma unroll
    for (int k = 0; k < 9; ++k) {
#pragma unroll
        for (int h = 0; h < 2; ++h) {
            short8 af = *(const short8*)(inN + (size_t)(rowc + k * R_BINS) * NC + h * 32 + q * 8);
            const ushort_t* wbb = wb + (size_t)((k * 2 + h) * 4) * 512 + lane * 8;
            short8 b0 = *(const short8*)(wbb);
            short8 b1v = *(const short8*)(wbb + 512);
            short8 b2v = *(const short8*)(wbb + 1024);
            short8 b3v = *(const short8*)(wbb + 1536);
            acc[0] = __builtin_amdgcn_mfma_f32_16x16x32_bf16(af, b0, acc[0], 0, 0, 0);
            acc[1] = __builtin_amdgcn_mfma_f32_16x16x32_bf16(af, b1v, acc[1], 0, 0, 0);
            acc[2] = __builtin_amdgcn_mfma_f32_16x16x32_bf16(af, b2v, acc[2], 0, 0, 0);
            acc[3] = __builtin_amdgcn_mfma_f32_16x16x32_bf16(af, b3v, acc[3], 0, 0, 0);
        }
    }

    ushort_t* outN = out + n * 64;
#pragma unroll
    for (int cot = 0; cot < 4; ++cot) {
        int co = cot * 16 + m;
        float bv = bias[co];
#pragma unroll
        for (int i = 0; i < 4; ++i) {
            int rowD = rowBase + q * 4 + i;
            float v = fmaxf(acc[cot][i] + bv, 0.f);
            if (rowD < MROWS) outN[(size_t)(rowD + outRowOff) * NC + co] = f2b(v);
        }
    }
}

// ---- inverse DHT: ushort4 gathers serve all 4 batches; rho prefetch; LDS transpose ----
__global__ __launch_bounds__(256) void k_idht(const ushort_t* __restrict__ buf3,
                                              const int* __restrict__ rho,
                                              float* __restrict__ outp) {
    __shared__ float tile[32 * 260];
    int t = threadIdx.x, lane = t & 63, wv = t >> 6;
    int P0 = blockIdx.x * 32;
    int pw = P0 + wv * 8;
    float4v accv[8];
#pragma unroll
    for (int i = 0; i < 8; ++i) accv[i] = (float4v){0.f, 0.f, 0.f, 0.f};
    const int* rp = rho + pw;
    int4 rv0 = *(const int4*)(rp);
    int4 rv1 = *(const int4*)(rp + 4);
    for (int a = 0; a < A_BINS; ++a) {
        int rr[8] = {rv0.x, rv0.y, rv0.z, rv0.w, rv1.x, rv1.y, rv1.z, rv1.w};
        if (a < A_BINS - 1) {
            rv0 = *(const int4*)(rp + (size_t)(a + 1) * HW);
            rv1 = *(const int4*)(rp + (size_t)(a + 1) * HW + 4);
        }
        const ushort_t* ba = buf3 + (size_t)a * (R_BINS * NC) + lane * 4;
#pragma unroll
        for (int i = 0; i < 8; ++i) {
            uint2 u = *(const uint2*)(ba + (size_t)rr[i] * NC);
            float4v v = {u2f(u.x << 16), u2f(u.x & 0xffff0000u),
                         u2f(u.y << 16), u2f(u.y & 0xffff0000u)};
            accv[i] += v;
        }
    }
#pragma unroll
    for (int i = 0; i < 8; ++i)
        *(float4v*)(tile + (size_t)(wv * 8 + i) * 260 + lane * 4) = accv[i];
    __syncthreads();
    int px = t & 31, nc0 = t >> 5;
#pragma unroll
    for (int k = 0; k < 32; ++k) {
        int nc = nc0 + k * 8;
        outp[(size_t)nc * HW + P0 + px] = tile[px * 260 + nc];
    }
}

extern "C" void kernel_launch(void* const* d_in, const int* in_sizes, int n_in,
                              void* d_out, int out_size, void* d_ws, size_t ws_size,
                              hipStream_t stream) {
    const float* x   = (const float*)d_in[0];
    const int*   rho = (const int*)d_in[1];
    const float* w1  = (const float*)d_in[2];
    const float* b1  = (const float*)d_in[3];
    const float* w2  = (const float*)d_in[4];
    const float* b2  = (const float*)d_in[5];
    const float* w3  = (const float*)d_in[6];
    const float* b3  = (const float*)d_in[7];
    float* outp = (float*)d_out;

    char* ws = (char*)d_ws;
    size_t off = 0;
    auto alloc = [&](size_t bytes) -> void* {
        void* p = ws + off;
        off = (off + bytes + 255) & ~(size_t)255;
        return p;
    };
    ushort_t* xb   = (ushort_t*)alloc((size_t)NC * HW * 2);             // 8 MB
    ushort_t* xbT  = (ushort_t*)alloc((size_t)NC * HW * 2);             // 8 MB
    int*      rhoT = (int*)alloc((size_t)A_BINS * HW * 4);              // 11.8 MB
    ushort_t* ht0  = (ushort_t*)alloc((size_t)AP * R_BINS * NC * 2);    // 17.5 MB
    ushort_t* bufA = (ushort_t*)alloc((size_t)AP * R_BINS * NC * 2);    // 17.5 MB
    ushort_t* bufB = (ushort_t*)alloc((size_t)AP * R_BINS * NC * 2);    // 17.5 MB
    ushort_t* buf3 = (ushort_t*)alloc((size_t)A_BINS * R_BINS * NC * 2);// 16.8 MB
    ushort_t* w2b  = (ushort_t*)alloc(36864 * 2);
    ushort_t* w3b  = (ushort_t*)alloc(36864 * 2);

    k_prep<<<dim3(2, 2, 256), 256, 0, stream>>>(x, xb, xbT);
    k_rhoT<<<dim3(2, 2, A_BINS), 256, 0, stream>>>(rho, rhoT);
    k_zero_pads<<<24, 256, 0, stream>>>(ht0, bufA, bufB);
    k_repack<<<dim3(144, 2), 256, 0, stream>>>(w2, w3, w2b, w3b);
    k_dht_s<<<dim3(A_BINS, NB), 256, 0, stream>>>(xb, xbT, rho, rhoT, ht0);
    k_conv1<<<dim3(R_BINS, A_BINS), 256, 0, stream>>>(ht0, w1, b1, bufA);
    k_gemm<<<dim3(512, NB), 256, 0, stream>>>(bufA, w2b, b2, bufB, 728);
    k_gemm<<<dim3(512, NB), 256, 0, stream>>>(bufB, w3b, b3, buf3, 0);
    k_idht<<<dim3(512), 256, 0, stream>>>(buf3, rho, outp);
}

// Round 4
// 465.794 us; speedup vs baseline: 9.7390x; 9.7390x over previous
//
#include <hip/hip_runtime.h>

typedef unsigned short ushort_t;
typedef __attribute__((ext_vector_type(8))) short short8;
typedef __attribute__((ext_vector_type(4))) float float4v;

#define HW 16384
#define A_BINS 180
#define R_BINS 182
#define AP 188              // A padded by 4 each side
#define CCH 64
#define NB 4
#define NC 256              // NB*CCH, nc-major inner dim of hough buffers
#define MROWS (A_BINS * R_BINS)      // 32760
#define MPROWS (AP * R_BINS)         // 34216

static __device__ __forceinline__ float b2f(ushort_t u) {
    union { unsigned u32; float f; } c; c.u32 = ((unsigned)u) << 16; return c.f;
}
static __device__ __forceinline__ float u2f(unsigned u) {
    union { unsigned u32; float f; } c; c.u32 = u; return c.f;
}
static __device__ __forceinline__ ushort_t f2b(float f) {
    union { float f; unsigned u; } c; c.f = f;
    unsigned r = c.u + 0x7fffu + ((c.u >> 16) & 1u);   // RNE
    return (ushort_t)(r >> 16);
}
static __device__ __forceinline__ float4v cvt4(uint2 u) {
    return (float4v){u2f(u.x << 16), u2f(u.x & 0xffff0000u),
                     u2f(u.y << 16), u2f(u.y & 0xffff0000u)};
}

// ---------------- transpose x [256][16384] f32 -> xT [16384][256] bf16 ----------------
__global__ __launch_bounds__(256) void k_transpose(const float* __restrict__ x,
                                                   ushort_t* __restrict__ xT) {
    __shared__ float tile[64][65];
    int t = threadIdx.x, lane = t & 63, g = t >> 6;
    int pBase = blockIdx.x * 64;     // pixel tile
    int ncBase = blockIdx.y * 64;    // channel tile
#pragma unroll
    for (int i = 0; i < 16; ++i) {
        int ncl = g + i * 4;
        tile[ncl][lane] = x[(size_t)(ncBase + ncl) * HW + pBase + lane];
    }
    __syncthreads();
#pragma unroll
    for (int i = 0; i < 16; ++i) {
        int pl = g + i * 4;
        xT[(size_t)(pBase + pl) * 256 + ncBase + lane] = f2b(tile[lane][pl]);
    }
}

// ---- zero the A-padding rows of the 3 padded nc-major buffers ----
__global__ __launch_bounds__(256) void k_zero_pads(ushort_t* __restrict__ ht0,
                                                   ushort_t* __restrict__ bufA,
                                                   ushort_t* __restrict__ bufB) {
    int b = blockIdx.x >> 3, j = blockIdx.x & 7;
    int ap = (j < 4) ? j : (184 + (j - 4));
    ushort_t* base = (b == 0 ? ht0 : (b == 1 ? bufA : bufB));
    uint4* p = (uint4*)(base + (size_t)ap * (R_BINS * NC));
    int n16 = R_BINS * NC / 8;      // uint4 = 8 ushorts
    for (int i = threadIdx.x; i < n16; i += 256) p[i] = (uint4){0, 0, 0, 0};
}

// ---- repack conv weights (64,64,9) f32 -> MFMA B-fragment bf16 ----
__global__ __launch_bounds__(256) void k_repack(const float* __restrict__ w2,
                                                const float* __restrict__ w3,
                                                ushort_t* __restrict__ w2b,
                                                ushort_t* __restrict__ w3b) {
    const float* w = blockIdx.y ? w3 : w2;
    ushort_t* wb = blockIdx.y ? w3b : w2b;
    int idx = blockIdx.x * 256 + threadIdx.x;   // 0..36863
    int j = idx & 7;
    int lane = (idx >> 3) & 63;
    int cot = (idx >> 9) & 3;
    int h = (idx >> 11) & 1;
    int k = idx >> 12;
    int co = cot * 16 + (lane & 15);
    int ci = h * 32 + (lane >> 4) * 8 + j;
    wb[idx] = f2b(w[(co * 64 + ci) * 9 + k]);
}

// ---- build per-angle CSR: bin -> pixel list ----
__global__ __launch_bounds__(256) void k_csr(const int* __restrict__ rho,
                                             int* __restrict__ offs,
                                             ushort_t* __restrict__ plist) {
    __shared__ int hist[4][R_BINS];    // per-wave sub-histograms
    __shared__ int tot[R_BINS];
    __shared__ int offl[R_BINS + 1];
    __shared__ int cur[4][R_BINS];
    int a = blockIdx.x, t = threadIdx.x, wv = t >> 6;
    for (int i = t; i < 4 * R_BINS; i += 256) ((int*)hist)[i] = 0;
    __syncthreads();
    const int* rA = rho + (size_t)a * HW;
#pragma unroll 4
    for (int i = 0; i < 64; ++i) {
        int r = rA[t + i * 256];
        atomicAdd(&hist[wv][r], 1);
    }
    __syncthreads();
    if (t < R_BINS) tot[t] = hist[0][t] + hist[1][t] + hist[2][t] + hist[3][t];
    __syncthreads();
    if (t == 0) {
        int s = 0;
        for (int r = 0; r < R_BINS; ++r) { offl[r] = s; s += tot[r]; }
        offl[R_BINS] = s;
    }
    __syncthreads();
    if (t < R_BINS) {
        int b = offl[t];
        cur[0][t] = b; b += hist[0][t];
        cur[1][t] = b; b += hist[1][t];
        cur[2][t] = b; b += hist[2][t];
        cur[3][t] = b;
    }
    if (t <= R_BINS) offs[a * (R_BINS + 1) + t] = offl[t];
    __syncthreads();
#pragma unroll 4
    for (int i = 0; i < 64; ++i) {
        int p = t + i * 256;
        int r = rA[p];
        int pos = atomicAdd(&cur[wv][r], 1);
        plist[(size_t)a * HW + pos] = (ushort_t)p;
    }
}

// ---- DHT gather, batch-merged: one 512B gather per pixel serves all 256 nc ----
__global__ __launch_bounds__(256) void k_dht_g4(const ushort_t* __restrict__ xT,
                                                const int* __restrict__ offs,
                                                const ushort_t* __restrict__ plist,
                                                ushort_t* __restrict__ ht0) {
    int a = blockIdx.x, part = blockIdx.y;     // grid (180, 8)
    int t = threadIdx.x, lane = t & 63, wv = t >> 6;
    int wslot = part * 4 + wv;                 // 0..31
    const ushort_t* xn = xT + lane * 4;
    const ushort_t* pl = plist + (size_t)a * HW;
    const int* offA = offs + a * (R_BINS + 1);
    size_t obase = (size_t)(a + 4) * (R_BINS * NC);
    for (int r = wslot; r < R_BINS; r += 32) {
        int off = offA[r], end = offA[r + 1];
        float4v acc = (float4v){0.f, 0.f, 0.f, 0.f};
        int j = off;
        for (; j + 8 <= end; j += 8) {
            int p0 = pl[j + 0]; int p1 = pl[j + 1];
            int p2 = pl[j + 2]; int p3 = pl[j + 3];
            int p4 = pl[j + 4]; int p5 = pl[j + 5];
            int p6 = pl[j + 6]; int p7 = pl[j + 7];
            uint2 u0 = *(const uint2*)(xn + (size_t)p0 * 256);
            uint2 u1 = *(const uint2*)(xn + (size_t)p1 * 256);
            uint2 u2 = *(const uint2*)(xn + (size_t)p2 * 256);
            uint2 u3 = *(const uint2*)(xn + (size_t)p3 * 256);
            uint2 u4 = *(const uint2*)(xn + (size_t)p4 * 256);
            uint2 u5 = *(const uint2*)(xn + (size_t)p5 * 256);
            uint2 u6 = *(const uint2*)(xn + (size_t)p6 * 256);
            uint2 u7 = *(const uint2*)(xn + (size_t)p7 * 256);
            acc += cvt4(u0); acc += cvt4(u1); acc += cvt4(u2); acc += cvt4(u3);
            acc += cvt4(u4); acc += cvt4(u5); acc += cvt4(u6); acc += cvt4(u7);
        }
        for (; j < end; ++j) {
            uint2 u = *(const uint2*)(xn + (size_t)pl[j] * 256);
            acc += cvt4(u);
        }
        unsigned lo = (unsigned)f2b(acc.x) | ((unsigned)f2b(acc.y) << 16);
        unsigned hi = (unsigned)f2b(acc.z) | ((unsigned)f2b(acc.w) << 16);
        *(uint2*)(ht0 + obase + (size_t)r * NC + lane * 4) = (uint2){lo, hi};
    }
}

// ---- depthwise (9,1) conv + bias + relu, nc-major ----
__global__ __launch_bounds__(256) void k_conv1(const ushort_t* __restrict__ ht0,
                                               const float* __restrict__ w1,
                                               const float* __restrict__ b1,
                                               ushort_t* __restrict__ bufA) {
    __shared__ float wl[576 + 64];
    int t = threadIdx.x;
    for (int i = t; i < 576; i += 256) wl[i] = w1[i];
    if (t < 64) wl[576 + t] = b1[t];
    __syncthreads();
    int c = t & 63;
    int r = blockIdx.x, a = blockIdx.y;
    float s = wl[576 + c];
    size_t base = ((size_t)a * R_BINS + r) * NC + t;
#pragma unroll
    for (int k = 0; k < 9; ++k)
        s += b2f(ht0[base + (size_t)k * (R_BINS * NC)]) * wl[c * 9 + k];
    bufA[((size_t)(a + 4) * R_BINS + r) * NC + t] = f2b(fmaxf(s, 0.f));
}

// ---- dense (9,1) conv as MFMA GEMM, nc-major strides ----
__global__ __launch_bounds__(256) void k_gemm(const ushort_t* __restrict__ in,
                                              const ushort_t* __restrict__ wb,
                                              const float* __restrict__ bias,
                                              ushort_t* __restrict__ out,
                                              int outRowOff) {
    int t = threadIdx.x, lane = t & 63, wv = t >> 6;
    int m = lane & 15, q = lane >> 4;
    int n = blockIdx.y;
    int rowBase = blockIdx.x * 64 + wv * 16;
    int row = rowBase + m;
    int rowc = row < MROWS ? row : (MROWS - 1);
    const ushort_t* inN = in + n * 64;
    float4v acc[4];
#pragma unroll
    for (int i = 0; i < 4; ++i) acc[i] = (float4v){0.f, 0.f, 0.f, 0.f};

#pragma unroll
    for (int k = 0; k < 9; ++k) {
#pragma unroll
        for (int h = 0; h < 2; ++h) {
            short8 af = *(const short8*)(inN + (size_t)(rowc + k * R_BINS) * NC + h * 32 + q * 8);
            const ushort_t* wbb = wb + (size_t)((k * 2 + h) * 4) * 512 + lane * 8;
            short8 b0 = *(const short8*)(wbb);
            short8 b1v = *(const short8*)(wbb + 512);
            short8 b2v = *(const short8*)(wbb + 1024);
            short8 b3v = *(const short8*)(wbb + 1536);
            acc[0] = __builtin_amdgcn_mfma_f32_16x16x32_bf16(af, b0, acc[0], 0, 0, 0);
            acc[1] = __builtin_amdgcn_mfma_f32_16x16x32_bf16(af, b1v, acc[1], 0, 0, 0);
            acc[2] = __builtin_amdgcn_mfma_f32_16x16x32_bf16(af, b2v, acc[2], 0, 0, 0);
            acc[3] = __builtin_amdgcn_mfma_f32_16x16x32_bf16(af, b3v, acc[3], 0, 0, 0);
        }
    }

    ushort_t* outN = out + n * 64;
#pragma unroll
    for (int cot = 0; cot < 4; ++cot) {
        int co = cot * 16 + m;
        float bv = bias[co];
#pragma unroll
        for (int i = 0; i < 4; ++i) {
            int rowD = rowBase + q * 4 + i;
            float v = fmaxf(acc[cot][i] + bv, 0.f);
            if (rowD < MROWS) outN[(size_t)(rowD + outRowOff) * NC + co] = f2b(v);
        }
    }
}

// ---- inverse DHT: batch-merged uint2 gathers; rho prefetch; LDS transpose ----
__global__ __launch_bounds__(256) void k_idht(const ushort_t* __restrict__ buf3,
                                              const int* __restrict__ rho,
                                              float* __restrict__ outp) {
    __shared__ float tile[32 * 260];
    int t = threadIdx.x, lane = t & 63, wv = t >> 6;
    int P0 = blockIdx.x * 32;
    int pw = P0 + wv * 8;
    float4v accv[8];
#pragma unroll
    for (int i = 0; i < 8; ++i) accv[i] = (float4v){0.f, 0.f, 0.f, 0.f};
    const int* rp = rho + pw;
    int4 rv0 = *(const int4*)(rp);
    int4 rv1 = *(const int4*)(rp + 4);
    for (int a = 0; a < A_BINS; ++a) {
        int rr[8] = {rv0.x, rv0.y, rv0.z, rv0.w, rv1.x, rv1.y, rv1.z, rv1.w};
        if (a < A_BINS - 1) {
            rv0 = *(const int4*)(rp + (size_t)(a + 1) * HW);
            rv1 = *(const int4*)(rp + (size_t)(a + 1) * HW + 4);
        }
        const ushort_t* ba = buf3 + (size_t)a * (R_BINS * NC) + lane * 4;
#pragma unroll
        for (int i = 0; i < 8; ++i) {
            uint2 u = *(const uint2*)(ba + (size_t)rr[i] * NC);
            accv[i] += cvt4(u);
        }
    }
#pragma unroll
    for (int i = 0; i < 8; ++i)
        *(float4v*)(tile + (size_t)(wv * 8 + i) * 260 + lane * 4) = accv[i];
    __syncthreads();
    int px = t & 31, nc0 = t >> 5;
#pragma unroll
    for (int k = 0; k < 32; ++k) {
        int nc = nc0 + k * 8;
        outp[(size_t)nc * HW + P0 + px] = tile[px * 260 + nc];
    }
}

extern "C" void kernel_launch(void* const* d_in, const int* in_sizes, int n_in,
                              void* d_out, int out_size, void* d_ws, size_t ws_size,
                              hipStream_t stream) {
    const float* x   = (const float*)d_in[0];
    const int*   rho = (const int*)d_in[1];
    const float* w1  = (const float*)d_in[2];
    const float* b1  = (const float*)d_in[3];
    const float* w2  = (const float*)d_in[4];
    const float* b2  = (const float*)d_in[5];
    const float* w3  = (const float*)d_in[6];
    const float* b3  = (const float*)d_in[7];
    float* outp = (float*)d_out;

    char* ws = (char*)d_ws;
    size_t off = 0;
    auto alloc = [&](size_t bytes) -> void* {
        void* p = ws + off;
        off = (off + bytes + 255) & ~(size_t)255;
        return p;
    };
    ushort_t* xT    = (ushort_t*)alloc((size_t)HW * NC * 2);             // 8 MB
    ushort_t* ht0   = (ushort_t*)alloc((size_t)AP * R_BINS * NC * 2);    // 17.5 MB
    ushort_t* bufA  = (ushort_t*)alloc((size_t)AP * R_BINS * NC * 2);    // 17.5 MB
    ushort_t* bufB  = (ushort_t*)alloc((size_t)AP * R_BINS * NC * 2);    // 17.5 MB
    ushort_t* buf3  = (ushort_t*)alloc((size_t)A_BINS * R_BINS * NC * 2);// 16.8 MB
    ushort_t* w2b   = (ushort_t*)alloc(36864 * 2);
    ushort_t* w3b   = (ushort_t*)alloc(36864 * 2);
    int*      offs  = (int*)alloc((size_t)A_BINS * (R_BINS + 1) * 4);    // 132 KB
    ushort_t* plist = (ushort_t*)alloc((size_t)A_BINS * HW * 2);         // 5.9 MB

    k_transpose<<<dim3(256, 4), 256, 0, stream>>>(x, xT);
    k_zero_pads<<<24, 256, 0, stream>>>(ht0, bufA, bufB);
    k_repack<<<dim3(144, 2), 256, 0, stream>>>(w2, w3, w2b, w3b);
    k_csr<<<A_BINS, 256, 0, stream>>>(rho, offs, plist);
    k_dht_g4<<<dim3(A_BINS, 8), 256, 0, stream>>>(xT, offs, plist, ht0);
    k_conv1<<<dim3(R_BINS, A_BINS), 256, 0, stream>>>(ht0, w1, b1, bufA);
    k_gemm<<<dim3(512, NB), 256, 0, stream>>>(bufA, w2b, b2, bufB, 728);
    k_gemm<<<dim3(512, NB), 256, 0, stream>>>(bufB, w3b, b3, buf3, 0);
    k_idht<<<dim3(512), 256, 0, stream>>>(buf3, rho, outp);
}

// Round 5
// 447.662 us; speedup vs baseline: 10.1335x; 1.0405x over previous
//
#include <hip/hip_runtime.h>

typedef unsigned short ushort_t;
typedef __attribute__((ext_vector_type(8))) short short8;
typedef __attribute__((ext_vector_type(4))) float float4v;

#define HW 16384
#define A_BINS 180
#define R_BINS 182
#define AP 188              // A padded by 4 each side
#define CCH 64
#define NB 4
#define NC 256              // NB*CCH, nc-major inner dim of hough buffers
#define MROWS (A_BINS * R_BINS)      // 32760
#define MPROWS (AP * R_BINS)         // 34216

static __device__ __forceinline__ float b2f(ushort_t u) {
    union { unsigned u32; float f; } c; c.u32 = ((unsigned)u) << 16; return c.f;
}
static __device__ __forceinline__ float u2f(unsigned u) {
    union { unsigned u32; float f; } c; c.u32 = u; return c.f;
}
static __device__ __forceinline__ ushort_t f2b(float f) {
    union { float f; unsigned u; } c; c.f = f;
    unsigned r = c.u + 0x7fffu + ((c.u >> 16) & 1u);   // RNE
    return (ushort_t)(r >> 16);
}
static __device__ __forceinline__ float4v cvt4(uint2 u) {
    return (float4v){u2f(u.x << 16), u2f(u.x & 0xffff0000u),
                     u2f(u.y << 16), u2f(u.y & 0xffff0000u)};
}

// ---------------- transpose x [256][16384] f32 -> xT [16384][256] bf16 ----------------
__global__ __launch_bounds__(256) void k_transpose(const float* __restrict__ x,
                                                   ushort_t* __restrict__ xT) {
    __shared__ float tile[64][65];
    int t = threadIdx.x, lane = t & 63, g = t >> 6;
    int pBase = blockIdx.x * 64;     // pixel tile
    int ncBase = blockIdx.y * 64;    // channel tile
#pragma unroll
    for (int i = 0; i < 16; ++i) {
        int ncl = g + i * 4;
        tile[ncl][lane] = x[(size_t)(ncBase + ncl) * HW + pBase + lane];
    }
    __syncthreads();
#pragma unroll
    for (int i = 0; i < 16; ++i) {
        int pl = g + i * 4;
        xT[(size_t)(pBase + pl) * 256 + ncBase + lane] = f2b(tile[lane][pl]);
    }
}

// ---- setup: zero A-pad rows (blocks 0..23) + repack weights (blocks 24..311) ----
__global__ __launch_bounds__(256) void k_setup(ushort_t* __restrict__ ht0,
                                               ushort_t* __restrict__ bufA,
                                               ushort_t* __restrict__ bufB,
                                               const float* __restrict__ w2,
                                               const float* __restrict__ w3,
                                               ushort_t* __restrict__ w2b,
                                               ushort_t* __restrict__ w3b) {
    int blk = blockIdx.x, t = threadIdx.x;
    if (blk < 24) {
        int b = blk >> 3, j = blk & 7;
        int ap = (j < 4) ? j : (184 + (j - 4));
        ushort_t* base = (b == 0 ? ht0 : (b == 1 ? bufA : bufB));
        uint4* p = (uint4*)(base + (size_t)ap * (R_BINS * NC));
        int n16 = R_BINS * NC / 8;
        for (int i = t; i < n16; i += 256) p[i] = (uint4){0, 0, 0, 0};
        return;
    }
    int rep = blk - 24;                  // 0..287
    const float* w = (rep >= 144) ? w3 : w2;
    ushort_t* wb = (rep >= 144) ? w3b : w2b;
    int idx = (rep % 144) * 256 + t;     // 0..36863
    int j = idx & 7;
    int lane = (idx >> 3) & 63;
    int cot = (idx >> 9) & 3;
    int h = (idx >> 11) & 1;
    int k = idx >> 12;
    int co = cot * 16 + (lane & 15);
    int ci = h * 32 + (lane >> 4) * 8 + j;
    wb[idx] = f2b(w[(co * 64 + ci) * 9 + k]);
}

// ---- build per-angle CSR: bin -> pixel list ----
__global__ __launch_bounds__(256) void k_csr(const int* __restrict__ rho,
                                             int* __restrict__ offs,
                                             ushort_t* __restrict__ plist) {
    __shared__ int hist[4][R_BINS];    // per-wave sub-histograms
    __shared__ int tot[R_BINS];
    __shared__ int offl[R_BINS + 1];
    __shared__ int cur[4][R_BINS];
    int a = blockIdx.x, t = threadIdx.x, wv = t >> 6;
    for (int i = t; i < 4 * R_BINS; i += 256) ((int*)hist)[i] = 0;
    __syncthreads();
    const int* rA = rho + (size_t)a * HW;
#pragma unroll 4
    for (int i = 0; i < 64; ++i) {
        int r = rA[t + i * 256];
        atomicAdd(&hist[wv][r], 1);
    }
    __syncthreads();
    if (t < R_BINS) tot[t] = hist[0][t] + hist[1][t] + hist[2][t] + hist[3][t];
    __syncthreads();
    if (t == 0) {
        int s = 0;
        for (int r = 0; r < R_BINS; ++r) { offl[r] = s; s += tot[r]; }
        offl[R_BINS] = s;
    }
    __syncthreads();
    if (t < R_BINS) {
        int b = offl[t];
        cur[0][t] = b; b += hist[0][t];
        cur[1][t] = b; b += hist[1][t];
        cur[2][t] = b; b += hist[2][t];
        cur[3][t] = b;
    }
    if (t <= R_BINS) offs[a * (R_BINS + 1) + t] = offl[t];
    __syncthreads();
#pragma unroll 4
    for (int i = 0; i < 64; ++i) {
        int p = t + i * 256;
        int r = rA[p];
        int pos = atomicAdd(&cur[wv][r], 1);
        plist[(size_t)a * HW + pos] = (ushort_t)p;
    }
}

// ---- DHT gather, batch-merged: one 512B gather per pixel serves all 256 nc ----
__global__ __launch_bounds__(256) void k_dht_g4(const ushort_t* __restrict__ xT,
                                                const int* __restrict__ offs,
                                                const ushort_t* __restrict__ plist,
                                                ushort_t* __restrict__ ht0) {
    int a = blockIdx.x, part = blockIdx.y;     // grid (180, 16)
    int t = threadIdx.x, lane = t & 63, wv = t >> 6;
    int wslot = part * 4 + wv;                 // 0..63
    const ushort_t* xn = xT + lane * 4;
    const ushort_t* pl = plist + (size_t)a * HW;
    const int* offA = offs + a * (R_BINS + 1);
    size_t obase = (size_t)(a + 4) * (R_BINS * NC);
    for (int r = wslot; r < R_BINS; r += 64) {
        int off = offA[r], end = offA[r + 1];
        float4v acc = (float4v){0.f, 0.f, 0.f, 0.f};
        int j = off;
        // align j to 8 (plist base is 16B-aligned; uint4 loads need j%8==0)
        while (j < end && (j & 7)) {
            uint2 u = *(const uint2*)(xn + (size_t)pl[j] * 256);
            acc += cvt4(u);
            ++j;
        }
        for (; j + 16 <= end; j += 16) {
            uint4 iv0 = *(const uint4*)(pl + j);
            uint4 iv1 = *(const uint4*)(pl + j + 8);
            uint2 u0 = *(const uint2*)(xn + (size_t)(iv0.x & 0xffff) * 256);
            uint2 u1 = *(const uint2*)(xn + (size_t)(iv0.x >> 16) * 256);
            uint2 u2 = *(const uint2*)(xn + (size_t)(iv0.y & 0xffff) * 256);
            uint2 u3 = *(const uint2*)(xn + (size_t)(iv0.y >> 16) * 256);
            uint2 u4 = *(const uint2*)(xn + (size_t)(iv0.z & 0xffff) * 256);
            uint2 u5 = *(const uint2*)(xn + (size_t)(iv0.z >> 16) * 256);
            uint2 u6 = *(const uint2*)(xn + (size_t)(iv0.w & 0xffff) * 256);
            uint2 u7 = *(const uint2*)(xn + (size_t)(iv0.w >> 16) * 256);
            uint2 u8 = *(const uint2*)(xn + (size_t)(iv1.x & 0xffff) * 256);
            uint2 u9 = *(const uint2*)(xn + (size_t)(iv1.x >> 16) * 256);
            uint2 ua = *(const uint2*)(xn + (size_t)(iv1.y & 0xffff) * 256);
            uint2 ub = *(const uint2*)(xn + (size_t)(iv1.y >> 16) * 256);
            uint2 uc = *(const uint2*)(xn + (size_t)(iv1.z & 0xffff) * 256);
            uint2 ud = *(const uint2*)(xn + (size_t)(iv1.z >> 16) * 256);
            uint2 ue = *(const uint2*)(xn + (size_t)(iv1.w & 0xffff) * 256);
            uint2 uf = *(const uint2*)(xn + (size_t)(iv1.w >> 16) * 256);
            acc += cvt4(u0); acc += cvt4(u1); acc += cvt4(u2); acc += cvt4(u3);
            acc += cvt4(u4); acc += cvt4(u5); acc += cvt4(u6); acc += cvt4(u7);
            acc += cvt4(u8); acc += cvt4(u9); acc += cvt4(ua); acc += cvt4(ub);
            acc += cvt4(uc); acc += cvt4(ud); acc += cvt4(ue); acc += cvt4(uf);
        }
        for (; j + 8 <= end; j += 8) {
            uint4 iv0 = *(const uint4*)(pl + j);
            uint2 u0 = *(const uint2*)(xn + (size_t)(iv0.x & 0xffff) * 256);
            uint2 u1 = *(const uint2*)(xn + (size_t)(iv0.x >> 16) * 256);
            uint2 u2 = *(const uint2*)(xn + (size_t)(iv0.y & 0xffff) * 256);
            uint2 u3 = *(const uint2*)(xn + (size_t)(iv0.y >> 16) * 256);
            uint2 u4 = *(const uint2*)(xn + (size_t)(iv0.z & 0xffff) * 256);
            uint2 u5 = *(const uint2*)(xn + (size_t)(iv0.z >> 16) * 256);
            uint2 u6 = *(const uint2*)(xn + (size_t)(iv0.w & 0xffff) * 256);
            uint2 u7 = *(const uint2*)(xn + (size_t)(iv0.w >> 16) * 256);
            acc += cvt4(u0); acc += cvt4(u1); acc += cvt4(u2); acc += cvt4(u3);
            acc += cvt4(u4); acc += cvt4(u5); acc += cvt4(u6); acc += cvt4(u7);
        }
        for (; j < end; ++j) {
            uint2 u = *(const uint2*)(xn + (size_t)pl[j] * 256);
            acc += cvt4(u);
        }
        unsigned lo = (unsigned)f2b(acc.x) | ((unsigned)f2b(acc.y) << 16);
        unsigned hi = (unsigned)f2b(acc.z) | ((unsigned)f2b(acc.w) << 16);
        *(uint2*)(ht0 + obase + (size_t)r * NC + lane * 4) = (uint2){lo, hi};
    }
}

// ---- depthwise (9,1) conv + bias + relu, nc-major ----
__global__ __launch_bounds__(256) void k_conv1(const ushort_t* __restrict__ ht0,
                                               const float* __restrict__ w1,
                                               const float* __restrict__ b1,
                                               ushort_t* __restrict__ bufA) {
    __shared__ float wl[576 + 64];
    int t = threadIdx.x;
    for (int i = t; i < 576; i += 256) wl[i] = w1[i];
    if (t < 64) wl[576 + t] = b1[t];
    __syncthreads();
    int c = t & 63;
    int r = blockIdx.x, a = blockIdx.y;
    float s = wl[576 + c];
    size_t base = ((size_t)a * R_BINS + r) * NC + t;
#pragma unroll
    for (int k = 0; k < 9; ++k)
        s += b2f(ht0[base + (size_t)k * (R_BINS * NC)]) * wl[c * 9 + k];
    bufA[((size_t)(a + 4) * R_BINS + r) * NC + t] = f2b(fmaxf(s, 0.f));
}

// ---- dense (9,1) conv as MFMA GEMM, nc-major strides ----
__global__ __launch_bounds__(256) void k_gemm(const ushort_t* __restrict__ in,
                                              const ushort_t* __restrict__ wb,
                                              const float* __restrict__ bias,
                                              ushort_t* __restrict__ out,
                                              int outRowOff) {
    int t = threadIdx.x, lane = t & 63, wv = t >> 6;
    int m = lane & 15, q = lane >> 4;
    int n = blockIdx.y;
    int rowBase = blockIdx.x * 64 + wv * 16;
    int row = rowBase + m;
    int rowc = row < MROWS ? row : (MROWS - 1);
    const ushort_t* inN = in + n * 64;
    float4v acc[4];
#pragma unroll
    for (int i = 0; i < 4; ++i) acc[i] = (float4v){0.f, 0.f, 0.f, 0.f};

#pragma unroll
    for (int k = 0; k < 9; ++k) {
#pragma unroll
        for (int h = 0; h < 2; ++h) {
            short8 af = *(const short8*)(inN + (size_t)(rowc + k * R_BINS) * NC + h * 32 + q * 8);
            const ushort_t* wbb = wb + (size_t)((k * 2 + h) * 4) * 512 + lane * 8;
            short8 b0 = *(const short8*)(wbb);
            short8 b1v = *(const short8*)(wbb + 512);
            short8 b2v = *(const short8*)(wbb + 1024);
            short8 b3v = *(const short8*)(wbb + 1536);
            acc[0] = __builtin_amdgcn_mfma_f32_16x16x32_bf16(af, b0, acc[0], 0, 0, 0);
            acc[1] = __builtin_amdgcn_mfma_f32_16x16x32_bf16(af, b1v, acc[1], 0, 0, 0);
            acc[2] = __builtin_amdgcn_mfma_f32_16x16x32_bf16(af, b2v, acc[2], 0, 0, 0);
            acc[3] = __builtin_amdgcn_mfma_f32_16x16x32_bf16(af, b3v, acc[3], 0, 0, 0);
        }
    }

    ushort_t* outN = out + n * 64;
#pragma unroll
    for (int cot = 0; cot < 4; ++cot) {
        int co = cot * 16 + m;
        float bv = bias[co];
#pragma unroll
        for (int i = 0; i < 4; ++i) {
            int rowD = rowBase + q * 4 + i;
            float v = fmaxf(acc[cot][i] + bv, 0.f);
            if (rowD < MROWS) outN[(size_t)(rowD + outRowOff) * NC + co] = f2b(v);
        }
    }
}

// ---- inverse DHT: 512-thr blocks, 2-way angle split, batch-merged gathers ----
__global__ __launch_bounds__(512) void k_idht(const ushort_t* __restrict__ buf3,
                                              const int* __restrict__ rho,
                                              float* __restrict__ outp) {
    __shared__ float tile[2][256][33];   // 67.6 KB -> 2 blocks/CU, 16 waves/CU
    int t = threadIdx.x, lane = t & 63, wv = t >> 6;   // wv 0..7
    int grp = wv >> 2;       // angle half
    int wq = wv & 3;         // pixel quad
    int P0 = blockIdx.x * 32;
    int pw = P0 + wq * 8;
    float4v accv[8];
#pragma unroll
    for (int i = 0; i < 8; ++i) accv[i] = (float4v){0.f, 0.f, 0.f, 0.f};
    const int* rp = rho + pw;
    int a0 = grp * 90, a1 = a0 + 90;
    int4 rv0 = *(const int4*)(rp + (size_t)a0 * HW);
    int4 rv1 = *(const int4*)(rp + (size_t)a0 * HW + 4);
    for (int a = a0; a < a1; ++a) {
        int rr[8] = {rv0.x, rv0.y, rv0.z, rv0.w, rv1.x, rv1.y, rv1.z, rv1.w};
        if (a + 1 < a1) {
            rv0 = *(const int4*)(rp + (size_t)(a + 1) * HW);
            rv1 = *(const int4*)(rp + (size_t)(a + 1) * HW + 4);
        }
        const ushort_t* ba = buf3 + (size_t)a * (R_BINS * NC) + lane * 4;
#pragma unroll
        for (int i = 0; i < 8; ++i) {
            uint2 u = *(const uint2*)(ba + (size_t)rr[i] * NC);
            accv[i] += cvt4(u);
        }
    }
    float* tg = &tile[grp][0][0];
#pragma unroll
    for (int i = 0; i < 8; ++i) {
        int px = wq * 8 + i;
#pragma unroll
        for (int c = 0; c < 4; ++c)
            tg[(lane * 4 + c) * 33 + px] = accv[i][c];
    }
    __syncthreads();
    int px = t & 31, nc0 = t >> 5;    // nc0 0..15
    float* on = outp + P0 + px;
#pragma unroll
    for (int k = 0; k < 16; ++k) {
        int nc = nc0 + k * 16;
        on[(size_t)nc * HW] = tile[0][nc][px] + tile[1][nc][px];
    }
}

extern "C" void kernel_launch(void* const* d_in, const int* in_sizes, int n_in,
                              void* d_out, int out_size, void* d_ws, size_t ws_size,
                              hipStream_t stream) {
    const float* x   = (const float*)d_in[0];
    const int*   rho = (const int*)d_in[1];
    const float* w1  = (const float*)d_in[2];
    const float* b1  = (const float*)d_in[3];
    const float* w2  = (const float*)d_in[4];
    const float* b2  = (const float*)d_in[5];
    const float* w3  = (const float*)d_in[6];
    const float* b3  = (const float*)d_in[7];
    float* outp = (float*)d_out;

    char* ws = (char*)d_ws;
    size_t off = 0;
    auto alloc = [&](size_t bytes) -> void* {
        void* p = ws + off;
        off = (off + bytes + 255) & ~(size_t)255;
        return p;
    };
    ushort_t* xT    = (ushort_t*)alloc((size_t)HW * NC * 2);             // 8 MB
    ushort_t* ht0   = (ushort_t*)alloc((size_t)AP * R_BINS * NC * 2);    // 17.5 MB
    ushort_t* bufA  = (ushort_t*)alloc((size_t)AP * R_BINS * NC * 2);    // 17.5 MB
    ushort_t* bufB  = (ushort_t*)alloc((size_t)AP * R_BINS * NC * 2);    // 17.5 MB
    ushort_t* buf3  = (ushort_t*)alloc((size_t)A_BINS * R_BINS * NC * 2);// 16.8 MB
    ushort_t* w2b   = (ushort_t*)alloc(36864 * 2);
    ushort_t* w3b   = (ushort_t*)alloc(36864 * 2);
    int*      offs  = (int*)alloc((size_t)A_BINS * (R_BINS + 1) * 4);    // 132 KB
    ushort_t* plist = (ushort_t*)alloc((size_t)A_BINS * HW * 2);         // 5.9 MB

    k_transpose<<<dim3(256, 4), 256, 0, stream>>>(x, xT);
    k_setup<<<312, 256, 0, stream>>>(ht0, bufA, bufB, w2, w3, w2b, w3b);
    k_csr<<<A_BINS, 256, 0, stream>>>(rho, offs, plist);
    k_dht_g4<<<dim3(A_BINS, 16), 256, 0, stream>>>(xT, offs, plist, ht0);
    k_conv1<<<dim3(R_BINS, A_BINS), 256, 0, stream>>>(ht0, w1, b1, bufA);
    k_gemm<<<dim3(512, NB), 256, 0, stream>>>(bufA, w2b, b2, bufB, 728);
    k_gemm<<<dim3(512, NB), 256, 0, stream>>>(bufB, w3b, b3, buf3, 0);
    k_idht<<<dim3(512), 512, 0, stream>>>(buf3, rho, outp);
}

// Round 6
// 413.764 us; speedup vs baseline: 10.9637x; 1.0819x over previous
//
#include <hip/hip_runtime.h>

typedef unsigned short ushort_t;
typedef __attribute__((ext_vector_type(8))) short short8;
typedef __attribute__((ext_vector_type(4))) float float4v;

#define HW 16384
#define A_BINS 180
#define R_BINS 182
#define AP 188              // A padded by 4 each side
#define CCH 64
#define NB 4
#define NC 256              // NB*CCH, nc-major inner dim of hough buffers
#define MROWS (A_BINS * R_BINS)      // 32760
#define MPROWS (AP * R_BINS)         // 34216

static __device__ __forceinline__ float b2f(ushort_t u) {
    union { unsigned u32; float f; } c; c.u32 = ((unsigned)u) << 16; return c.f;
}
static __device__ __forceinline__ float u2f(unsigned u) {
    union { unsigned u32; float f; } c; c.u32 = u; return c.f;
}
static __device__ __forceinline__ ushort_t f2b(float f) {
    union { float f; unsigned u; } c; c.f = f;
    unsigned r = c.u + 0x7fffu + ((c.u >> 16) & 1u);   // RNE
    return (ushort_t)(r >> 16);
}
static __device__ __forceinline__ float4v cvt4(uint2 u) {
    return (float4v){u2f(u.x << 16), u2f(u.x & 0xffff0000u),
                     u2f(u.y << 16), u2f(u.y & 0xffff0000u)};
}

// ---------------- transpose x [256][16384] f32 -> xT [16384][256] bf16 ----------------
__global__ __launch_bounds__(256) void k_transpose(const float* __restrict__ x,
                                                   ushort_t* __restrict__ xT) {
    __shared__ float tile[64][65];
    int t = threadIdx.x, lane = t & 63, g = t >> 6;
    int pBase = blockIdx.x * 64;     // pixel tile
    int ncBase = blockIdx.y * 64;    // channel tile
#pragma unroll
    for (int i = 0; i < 16; ++i) {
        int ncl = g + i * 4;
        tile[ncl][lane] = x[(size_t)(ncBase + ncl) * HW + pBase + lane];
    }
    __syncthreads();
#pragma unroll
    for (int i = 0; i < 16; ++i) {
        int pl = g + i * 4;
        xT[(size_t)(pBase + pl) * 256 + ncBase + lane] = f2b(tile[lane][pl]);
    }
}

// ---- setup: zero A-pad rows (blocks 0..23) + repack weights (blocks 24..311) ----
__global__ __launch_bounds__(256) void k_setup(ushort_t* __restrict__ ht0,
                                               ushort_t* __restrict__ bufA,
                                               ushort_t* __restrict__ bufB,
                                               const float* __restrict__ w2,
                                               const float* __restrict__ w3,
                                               ushort_t* __restrict__ w2b,
                                               ushort_t* __restrict__ w3b) {
    int blk = blockIdx.x, t = threadIdx.x;
    if (blk < 24) {
        int b = blk >> 3, j = blk & 7;
        int ap = (j < 4) ? j : (184 + (j - 4));
        ushort_t* base = (b == 0 ? ht0 : (b == 1 ? bufA : bufB));
        uint4* p = (uint4*)(base + (size_t)ap * (R_BINS * NC));
        int n16 = R_BINS * NC / 8;
        for (int i = t; i < n16; i += 256) p[i] = (uint4){0, 0, 0, 0};
        return;
    }
    int rep = blk - 24;                  // 0..287
    const float* w = (rep >= 144) ? w3 : w2;
    ushort_t* wb = (rep >= 144) ? w3b : w2b;
    int idx = (rep % 144) * 256 + t;     // 0..36863
    int j = idx & 7;
    int lane = (idx >> 3) & 63;
    int cot = (idx >> 9) & 3;
    int h = (idx >> 11) & 1;
    int k = idx >> 12;
    int co = cot * 16 + (lane & 15);
    int ci = h * 32 + (lane >> 4) * 8 + j;
    wb[idx] = f2b(w[(co * 64 + ci) * 9 + k]);
}

// ---- build per-angle CSR: bin -> pixel list; LDS-staged, coalesced output ----
__global__ __launch_bounds__(256) void k_csr(const int* __restrict__ rho,
                                             int* __restrict__ offs,
                                             ushort_t* __restrict__ plist) {
    __shared__ int hist[4][R_BINS];    // per-wave sub-histograms
    __shared__ int tot[R_BINS];
    __shared__ int offl[R_BINS + 1];
    __shared__ int cur[4][R_BINS];
    __shared__ ushort_t sp[HW];        // 32 KB staging, bin-sorted pixel ids
    int a = blockIdx.x, t = threadIdx.x, lane = t & 63, wv = t >> 6;
    for (int i = t; i < 4 * R_BINS; i += 256) ((int*)hist)[i] = 0;
    __syncthreads();
    const int* rA = rho + (size_t)a * HW;
#pragma unroll 4
    for (int i = 0; i < 64; ++i) {
        int r = rA[t + i * 256];
        atomicAdd(&hist[wv][r], 1);
    }
    __syncthreads();
    if (t < R_BINS) tot[t] = hist[0][t] + hist[1][t] + hist[2][t] + hist[3][t];
    __syncthreads();
    if (wv == 0) {                       // wave-parallel exclusive scan, 3 bins/lane
        int b0 = lane * 3;
        int c0 = (b0     < R_BINS) ? tot[b0]     : 0;
        int c1 = (b0 + 1 < R_BINS) ? tot[b0 + 1] : 0;
        int c2 = (b0 + 2 < R_BINS) ? tot[b0 + 2] : 0;
        int sum = c0 + c1 + c2, inc = sum;
#pragma unroll
        for (int d = 1; d < 64; d <<= 1) {
            int vv = __shfl_up(inc, d);
            if (lane >= d) inc += vv;
        }
        int excl = inc - sum;
        if (b0     < R_BINS) offl[b0]     = excl;
        if (b0 + 1 < R_BINS) offl[b0 + 1] = excl + c0;
        if (b0 + 2 < R_BINS) offl[b0 + 2] = excl + c0 + c1;
        if (lane == 63) offl[R_BINS] = inc;
    }
    __syncthreads();
    if (t < R_BINS) {
        int b = offl[t];
        cur[0][t] = b; b += hist[0][t];
        cur[1][t] = b; b += hist[1][t];
        cur[2][t] = b; b += hist[2][t];
        cur[3][t] = b;
    }
    if (t <= R_BINS) offs[a * (R_BINS + 1) + t] = offl[t];
    __syncthreads();
#pragma unroll 4
    for (int i = 0; i < 64; ++i) {
        int p = t + i * 256;
        int r = rA[p];
        int pos = atomicAdd(&cur[wv][r], 1);
        sp[pos] = (ushort_t)p;
    }
    __syncthreads();
    const uint4* spv = (const uint4*)sp;
    uint4* plv = (uint4*)(plist + (size_t)a * HW);
    for (int i = t; i < HW / 8; i += 256) plv[i] = spv[i];
}

// ---- DHT gather, batch-merged: one 512B gather per pixel serves all 256 nc ----
__global__ __launch_bounds__(256) void k_dht_g4(const ushort_t* __restrict__ xT,
                                                const int* __restrict__ offs,
                                                const ushort_t* __restrict__ plist,
                                                ushort_t* __restrict__ ht0) {
    int a = blockIdx.x, part = blockIdx.y;     // grid (180, 16)
    int t = threadIdx.x, lane = t & 63, wv = t >> 6;
    int wslot = part * 4 + wv;                 // 0..63
    const ushort_t* xn = xT + lane * 4;
    const ushort_t* pl = plist + (size_t)a * HW;
    const int* offA = offs + a * (R_BINS + 1);
    size_t obase = (size_t)(a + 4) * (R_BINS * NC);
    for (int r = wslot; r < R_BINS; r += 64) {
        int off = offA[r], end = offA[r + 1];
        float4v acc = (float4v){0.f, 0.f, 0.f, 0.f};
        int j = off;
        while (j < end && (j & 7)) {
            uint2 u = *(const uint2*)(xn + (size_t)pl[j] * 256);
            acc += cvt4(u);
            ++j;
        }
        for (; j + 16 <= end; j += 16) {
            uint4 iv0 = *(const uint4*)(pl + j);
            uint4 iv1 = *(const uint4*)(pl + j + 8);
            uint2 u0 = *(const uint2*)(xn + (size_t)(iv0.x & 0xffff) * 256);
            uint2 u1 = *(const uint2*)(xn + (size_t)(iv0.x >> 16) * 256);
            uint2 u2 = *(const uint2*)(xn + (size_t)(iv0.y & 0xffff) * 256);
            uint2 u3 = *(const uint2*)(xn + (size_t)(iv0.y >> 16) * 256);
            uint2 u4 = *(const uint2*)(xn + (size_t)(iv0.z & 0xffff) * 256);
            uint2 u5 = *(const uint2*)(xn + (size_t)(iv0.z >> 16) * 256);
            uint2 u6 = *(const uint2*)(xn + (size_t)(iv0.w & 0xffff) * 256);
            uint2 u7 = *(const uint2*)(xn + (size_t)(iv0.w >> 16) * 256);
            uint2 u8 = *(const uint2*)(xn + (size_t)(iv1.x & 0xffff) * 256);
            uint2 u9 = *(const uint2*)(xn + (size_t)(iv1.x >> 16) * 256);
            uint2 ua = *(const uint2*)(xn + (size_t)(iv1.y & 0xffff) * 256);
            uint2 ub = *(const uint2*)(xn + (size_t)(iv1.y >> 16) * 256);
            uint2 uc = *(const uint2*)(xn + (size_t)(iv1.z & 0xffff) * 256);
            uint2 ud = *(const uint2*)(xn + (size_t)(iv1.z >> 16) * 256);
            uint2 ue = *(const uint2*)(xn + (size_t)(iv1.w & 0xffff) * 256);
            uint2 uf = *(const uint2*)(xn + (size_t)(iv1.w >> 16) * 256);
            acc += cvt4(u0); acc += cvt4(u1); acc += cvt4(u2); acc += cvt4(u3);
            acc += cvt4(u4); acc += cvt4(u5); acc += cvt4(u6); acc += cvt4(u7);
            acc += cvt4(u8); acc += cvt4(u9); acc += cvt4(ua); acc += cvt4(ub);
            acc += cvt4(uc); acc += cvt4(ud); acc += cvt4(ue); acc += cvt4(uf);
        }
        for (; j + 8 <= end; j += 8) {
            uint4 iv0 = *(const uint4*)(pl + j);
            uint2 u0 = *(const uint2*)(xn + (size_t)(iv0.x & 0xffff) * 256);
            uint2 u1 = *(const uint2*)(xn + (size_t)(iv0.x >> 16) * 256);
            uint2 u2 = *(const uint2*)(xn + (size_t)(iv0.y & 0xffff) * 256);
            uint2 u3 = *(const uint2*)(xn + (size_t)(iv0.y >> 16) * 256);
            uint2 u4 = *(const uint2*)(xn + (size_t)(iv0.z & 0xffff) * 256);
            uint2 u5 = *(const uint2*)(xn + (size_t)(iv0.z >> 16) * 256);
            uint2 u6 = *(const uint2*)(xn + (size_t)(iv0.w & 0xffff) * 256);
            uint2 u7 = *(const uint2*)(xn + (size_t)(iv0.w >> 16) * 256);
            acc += cvt4(u0); acc += cvt4(u1); acc += cvt4(u2); acc += cvt4(u3);
            acc += cvt4(u4); acc += cvt4(u5); acc += cvt4(u6); acc += cvt4(u7);
        }
        for (; j < end; ++j) {
            uint2 u = *(const uint2*)(xn + (size_t)pl[j] * 256);
            acc += cvt4(u);
        }
        unsigned lo = (unsigned)f2b(acc.x) | ((unsigned)f2b(acc.y) << 16);
        unsigned hi = (unsigned)f2b(acc.z) | ((unsigned)f2b(acc.w) << 16);
        *(uint2*)(ht0 + obase + (size_t)r * NC + lane * 4) = (uint2){lo, hi};
    }
}

// ---- depthwise (9,1) conv + bias + relu: register sliding window along a ----
// thread = (r, nc); block covers 30 output angles, reads each ht0 elem once
__global__ __launch_bounds__(256) void k_conv1(const ushort_t* __restrict__ ht0,
                                               const float* __restrict__ w1,
                                               const float* __restrict__ b1,
                                               ushort_t* __restrict__ bufA) {
    int t = threadIdx.x, c = t & 63;
    int r = blockIdx.x;              // 0..181
    int a0 = blockIdx.y * 30;        // output angle base (real coords)
    float wr[9];
#pragma unroll
    for (int k = 0; k < 9; ++k) wr[k] = w1[c * 9 + k];
    float bb = b1[c];
    // input padded-a index = a0 .. a0+37  (real a0-4 .. a0+33)
    const ushort_t* ip = ht0 + ((size_t)a0 * R_BINS + r) * NC + t;
    float v[38];
#pragma unroll
    for (int j = 0; j < 38; ++j) v[j] = b2f(ip[(size_t)j * (R_BINS * NC)]);
    ushort_t* op = bufA + ((size_t)(a0 + 4) * R_BINS + r) * NC + t;
#pragma unroll
    for (int i = 0; i < 30; ++i) {
        float s = bb;
#pragma unroll
        for (int k = 0; k < 9; ++k) s = fmaf(v[i + k], wr[k], s);
        op[(size_t)i * (R_BINS * NC)] = f2b(fmaxf(s, 0.f));
    }
}

// ---- dense (9,1) conv as MFMA GEMM: B staged in LDS, 64 rows/wave ----
__global__ __launch_bounds__(256) void k_gemm(const ushort_t* __restrict__ in,
                                              const ushort_t* __restrict__ wb,
                                              const float* __restrict__ bias,
                                              ushort_t* __restrict__ out,
                                              int outRowOff) {
    __shared__ ushort_t Bs[36864];   // 73.7 KB -> 2 blocks/CU
    int t = threadIdx.x, lane = t & 63, wv = t >> 6;
    {
        const uint4* src = (const uint4*)wb;
        uint4* dst = (uint4*)Bs;
        for (int i = t; i < 36864 / 8; i += 256) dst[i] = src[i];
    }
    __syncthreads();
    int m = lane & 15, q = lane >> 4;
    int n = blockIdx.y;
    int rowBase = blockIdx.x * 256 + wv * 64;
    const ushort_t* inN = in + n * 64;
    // per-tile clamped row element-offsets
    size_t rof[4];
#pragma unroll
    for (int tl = 0; tl < 4; ++tl) {
        int row = rowBase + tl * 16 + m;
        int rowc = row < MROWS ? row : (MROWS - 1);
        rof[tl] = (size_t)rowc * NC;
    }
    float4v acc[4][4];
#pragma unroll
    for (int tl = 0; tl < 4; ++tl)
#pragma unroll
        for (int i = 0; i < 4; ++i) acc[tl][i] = (float4v){0.f, 0.f, 0.f, 0.f};

#pragma unroll
    for (int k = 0; k < 9; ++k) {
#pragma unroll
        for (int h = 0; h < 2; ++h) {
            const ushort_t* base = inN + (size_t)k * (R_BINS * NC) + h * 32 + q * 8;
            short8 af0 = *(const short8*)(base + rof[0]);
            short8 af1 = *(const short8*)(base + rof[1]);
            short8 af2 = *(const short8*)(base + rof[2]);
            short8 af3 = *(const short8*)(base + rof[3]);
            const ushort_t* bl = Bs + (size_t)((k * 2 + h) * 4) * 512 + lane * 8;
            short8 b0 = *(const short8*)(bl);
            short8 b1v = *(const short8*)(bl + 512);
            short8 b2v = *(const short8*)(bl + 1024);
            short8 b3v = *(const short8*)(bl + 1536);
            acc[0][0] = __builtin_amdgcn_mfma_f32_16x16x32_bf16(af0, b0, acc[0][0], 0, 0, 0);
            acc[0][1] = __builtin_amdgcn_mfma_f32_16x16x32_bf16(af0, b1v, acc[0][1], 0, 0, 0);
            acc[0][2] = __builtin_amdgcn_mfma_f32_16x16x32_bf16(af0, b2v, acc[0][2], 0, 0, 0);
            acc[0][3] = __builtin_amdgcn_mfma_f32_16x16x32_bf16(af0, b3v, acc[0][3], 0, 0, 0);
            acc[1][0] = __builtin_amdgcn_mfma_f32_16x16x32_bf16(af1, b0, acc[1][0], 0, 0, 0);
            acc[1][1] = __builtin_amdgcn_mfma_f32_16x16x32_bf16(af1, b1v, acc[1][1], 0, 0, 0);
            acc[1][2] = __builtin_amdgcn_mfma_f32_16x16x32_bf16(af1, b2v, acc[1][2], 0, 0, 0);
            acc[1][3] = __builtin_amdgcn_mfma_f32_16x16x32_bf16(af1, b3v, acc[1][3], 0, 0, 0);
            acc[2][0] = __builtin_amdgcn_mfma_f32_16x16x32_bf16(af2, b0, acc[2][0], 0, 0, 0);
            acc[2][1] = __builtin_amdgcn_mfma_f32_16x16x32_bf16(af2, b1v, acc[2][1], 0, 0, 0);
            acc[2][2] = __builtin_amdgcn_mfma_f32_16x16x32_bf16(af2, b2v, acc[2][2], 0, 0, 0);
            acc[2][3] = __builtin_amdgcn_mfma_f32_16x16x32_bf16(af2, b3v, acc[2][3], 0, 0, 0);
            acc[3][0] = __builtin_amdgcn_mfma_f32_16x16x32_bf16(af3, b0, acc[3][0], 0, 0, 0);
            acc[3][1] = __builtin_amdgcn_mfma_f32_16x16x32_bf16(af3, b1v, acc[3][1], 0, 0, 0);
            acc[3][2] = __builtin_amdgcn_mfma_f32_16x16x32_bf16(af3, b2v, acc[3][2], 0, 0, 0);
            acc[3][3] = __builtin_amdgcn_mfma_f32_16x16x32_bf16(af3, b3v, acc[3][3], 0, 0, 0);
        }
    }

    ushort_t* outN = out + n * 64;
#pragma unroll
    for (int tl = 0; tl < 4; ++tl) {
#pragma unroll
        for (int cot = 0; cot < 4; ++cot) {
            int co = cot * 16 + m;
            float bv = bias[co];
#pragma unroll
            for (int i = 0; i < 4; ++i) {
                int rowD = rowBase + tl * 16 + q * 4 + i;
                float v = fmaxf(acc[tl][cot][i] + bv, 0.f);
                if (rowD < MROWS) outN[(size_t)(rowD + outRowOff) * NC + co] = f2b(v);
            }
        }
    }
}

// ---- inverse DHT: 512-thr blocks, 2-way angle split, batch-merged gathers ----
__global__ __launch_bounds__(512) void k_idht(const ushort_t* __restrict__ buf3,
                                              const int* __restrict__ rho,
                                              float* __restrict__ outp) {
    __shared__ float tile[2][256][33];   // 67.6 KB -> 2 blocks/CU, 16 waves/CU
    int t = threadIdx.x, lane = t & 63, wv = t >> 6;   // wv 0..7
    int grp = wv >> 2;       // angle half
    int wq = wv & 3;         // pixel quad
    int P0 = blockIdx.x * 32;
    int pw = P0 + wq * 8;
    float4v accv[8];
#pragma unroll
    for (int i = 0; i < 8; ++i) accv[i] = (float4v){0.f, 0.f, 0.f, 0.f};
    const int* rp = rho + pw;
    int a0 = grp * 90, a1 = a0 + 90;
    int4 rv0 = *(const int4*)(rp + (size_t)a0 * HW);
    int4 rv1 = *(const int4*)(rp + (size_t)a0 * HW + 4);
    for (int a = a0; a < a1; ++a) {
        int rr[8] = {rv0.x, rv0.y, rv0.z, rv0.w, rv1.x, rv1.y, rv1.z, rv1.w};
        if (a + 1 < a1) {
            rv0 = *(const int4*)(rp + (size_t)(a + 1) * HW);
            rv1 = *(const int4*)(rp + (size_t)(a + 1) * HW + 4);
        }
        const ushort_t* ba = buf3 + (size_t)a * (R_BINS * NC) + lane * 4;
#pragma unroll
        for (int i = 0; i < 8; ++i) {
            uint2 u = *(const uint2*)(ba + (size_t)rr[i] * NC);
            accv[i] += cvt4(u);
        }
    }
    float* tg = &tile[grp][0][0];
#pragma unroll
    for (int i = 0; i < 8; ++i) {
        int px = wq * 8 + i;
#pragma unroll
        for (int c = 0; c < 4; ++c)
            tg[(lane * 4 + c) * 33 + px] = accv[i][c];
    }
    __syncthreads();
    int px = t & 31, nc0 = t >> 5;    // nc0 0..15
    float* on = outp + P0 + px;
#pragma unroll
    for (int k = 0; k < 16; ++k) {
        int nc = nc0 + k * 16;
        on[(size_t)nc * HW] = tile[0][nc][px] + tile[1][nc][px];
    }
}

extern "C" void kernel_launch(void* const* d_in, const int* in_sizes, int n_in,
                              void* d_out, int out_size, void* d_ws, size_t ws_size,
                              hipStream_t stream) {
    const float* x   = (const float*)d_in[0];
    const int*   rho = (const int*)d_in[1];
    const float* w1  = (const float*)d_in[2];
    const float* b1  = (const float*)d_in[3];
    const float* w2  = (const float*)d_in[4];
    const float* b2  = (const float*)d_in[5];
    const float* w3  = (const float*)d_in[6];
    const float* b3  = (const float*)d_in[7];
    float* outp = (float*)d_out;

    char* ws = (char*)d_ws;
    size_t off = 0;
    auto alloc = [&](size_t bytes) -> void* {
        void* p = ws + off;
        off = (off + bytes + 255) & ~(size_t)255;
        return p;
    };
    ushort_t* xT    = (ushort_t*)alloc((size_t)HW * NC * 2);             // 8 MB
    ushort_t* ht0   = (ushort_t*)alloc((size_t)AP * R_BINS * NC * 2);    // 17.5 MB
    ushort_t* bufA  = (ushort_t*)alloc((size_t)AP * R_BINS * NC * 2);    // 17.5 MB
    ushort_t* bufB  = (ushort_t*)alloc((size_t)AP * R_BINS * NC * 2);    // 17.5 MB
    ushort_t* buf3  = (ushort_t*)alloc((size_t)A_BINS * R_BINS * NC * 2);// 16.8 MB
    ushort_t* w2b   = (ushort_t*)alloc(36864 * 2);
    ushort_t* w3b   = (ushort_t*)alloc(36864 * 2);
    int*      offs  = (int*)alloc((size_t)A_BINS * (R_BINS + 1) * 4);    // 132 KB
    ushort_t* plist = (ushort_t*)alloc((size_t)A_BINS * HW * 2);         // 5.9 MB

    k_transpose<<<dim3(256, 4), 256, 0, stream>>>(x, xT);
    k_setup<<<312, 256, 0, stream>>>(ht0, bufA, bufB, w2, w3, w2b, w3b);
    k_csr<<<A_BINS, 256, 0, stream>>>(rho, offs, plist);
    k_dht_g4<<<dim3(A_BINS, 16), 256, 0, stream>>>(xT, offs, plist, ht0);
    k_conv1<<<dim3(R_BINS, 6), 256, 0, stream>>>(ht0, w1, b1, bufA);
    k_gemm<<<dim3(128, NB), 256, 0, stream>>>(bufA, w2b, b2, bufB, 728);
    k_gemm<<<dim3(128, NB), 256, 0, stream>>>(bufB, w3b, b3, buf3, 0);
    k_idht<<<dim3(512), 512, 0, stream>>>(buf3, rho, outp);
}